// Round 1
// baseline (580.216 us; speedup 1.0000x reference)
//
#include <hip/hip_runtime.h>
#include <cfloat>
#include <cmath>

// ---------------- types ----------------
typedef __attribute__((ext_vector_type(8))) short bf16x8;   // 8 bf16 (4 VGPRs) — MFMA A/B frag
typedef __attribute__((ext_vector_type(4))) float f32x4;    // MFMA C/D frag

__device__ __forceinline__ short f2bf(float f) {
    // fp32 -> bf16 round-to-nearest-even (inputs finite)
    unsigned u = __float_as_uint(f);
    u += 0x7fffu + ((u >> 16) & 1u);
    return (short)(u >> 16);
}

// ---------------- problem sizes ----------------
#define BATCH 64
#define KDIM  150528          // 3*224*224
#define NEMB  512
#define HIN_W 812             // 512 + 300
#define HID   400
#define ROWS  192             // B*C
#define RLEN  50176           // 224*224
#define RF4   12544           // RLEN/4
#define NBINS 100

// GEMM tiling: grid (112 K-chunks x 8 N-tiles of 64) = 896 blocks -> ALL co-resident at 4/CU
#define NCHUNK 112
#define KC     1344
#define NTILE  64
#define BK     64
#define NSLAB  (KC / BK)      // 21
#define LDA    72             // 64 + 8 bf16 pad: 144 B row stride -> conflict-free b128 frag reads

// ---------------- ws layout (float offsets) ----------------
#define WS_HIN  0                             // 64*812 = 51968
#define WS_H    (WS_HIN + BATCH*HIN_W)        // 64*400 = 25600
#define WS_T    (WS_H + BATCH*HID)            // 64*1400 = 89600
#define WS_XBF  (WS_T + BATCH*1400)           // bf16 x: 192*50176 shorts (16B-aligned byte offset)

// ================= K1: fused per-row minmax + histogram + bf16 emit + bias preset =================
// One block per (b,c) row: minmax needs no global atomics, bins live only in LDS,
// and the hist pass re-reads the row it just streamed (L2-local on the same XCD).
// Also pre-sets h_in[:, :512] = base_b so the GEMM can atomicAdd directly.
__global__ __launch_bounds__(1024) void k_fuse(const float* __restrict__ x,
                                               const float* __restrict__ base_b,
                                               float* __restrict__ ws) {
    int row = blockIdx.x;                    // 0..191
    int tid = threadIdx.x, lane = tid & 63, wave = tid >> 6;   // 16 waves

    // bias preset for the GEMM atomic epilogue (128 blocks x 256 entries = 32768 exact)
    if (row < 128 && tid < 256) {
        int o = row * 256 + tid;
        ws[WS_HIN + (o >> 9) * HIN_W + (o & 511)] = base_b[o & 511];
    }

    const float4* p = (const float4*)(x + (size_t)row * RLEN);   // 12544 float4, 16B aligned

    // ---- pass 1: row min/max ----
    float mn = FLT_MAX, mx = -FLT_MAX;
#pragma unroll 4
    for (int it = 0; it < 12; ++it) {
        float4 v = p[tid + it * 1024];
        mn = fminf(mn, fminf(fminf(v.x, v.y), fminf(v.z, v.w)));
        mx = fmaxf(mx, fmaxf(fmaxf(v.x, v.y), fmaxf(v.z, v.w)));
    }
    if (tid < 256) {   // tail: 12288..12543
        float4 v = p[12288 + tid];
        mn = fminf(mn, fminf(fminf(v.x, v.y), fminf(v.z, v.w)));
        mx = fmaxf(mx, fmaxf(fmaxf(v.x, v.y), fmaxf(v.z, v.w)));
    }
#pragma unroll
    for (int m = 1; m < 64; m <<= 1) {
        mn = fminf(mn, __shfl_xor(mn, m, 64));
        mx = fmaxf(mx, __shfl_xor(mx, m, 64));
    }

    __shared__ float smn[16], smx[16];
    __shared__ float s_mn, s_w;
    __shared__ unsigned bins[16][NBINS];     // per-wave private histograms (6.4 KB)

    if (lane == 0) { smn[wave] = mn; smx[wave] = mx; }
    __syncthreads();

    // zero bins (all threads) while wave 0 finishes the cross-wave reduce
    for (int i = tid; i < 16 * NBINS; i += 1024) bins[i / NBINS][i % NBINS] = 0u;
    if (tid < 16) {
        float a = smn[tid], b2 = smx[tid];
#pragma unroll
        for (int m = 1; m < 16; m <<= 1) {
            a  = fminf(a,  __shfl_xor(a,  m, 64));
            b2 = fmaxf(b2, __shfl_xor(b2, m, 64));
        }
        if (tid == 0) { s_mn = a; s_w = (b2 > a) ? (b2 - a) : 1.0f; }
    }
    __syncthreads();

    // ---- pass 2: histogram (exact reference fp32 op sequence) + bf16 emit ----
    float mnv = s_mn, wv = s_w;
    short* xrow = (short*)(ws + WS_XBF) + (size_t)row * RLEN;
    unsigned* mybins = bins[wave];
    for (int it = 0; it < 12; ++it) {
        int i = tid + it * 1024;
        float4 v = p[i];
        float e[4] = {v.x, v.y, v.z, v.w};
#pragma unroll
        for (int j = 0; j < 4; ++j) {
            int idx = (int)floorf((e[j] - mnv) / wv * 100.0f);
            idx = idx < 0 ? 0 : (idx > 99 ? 99 : idx);
            atomicAdd(&mybins[idx], 1u);
        }
        *(short4*)&xrow[4 * i] = make_short4(f2bf(v.x), f2bf(v.y), f2bf(v.z), f2bf(v.w));
    }
    if (tid < 256) {
        int i = 12288 + tid;
        float4 v = p[i];
        float e[4] = {v.x, v.y, v.z, v.w};
#pragma unroll
        for (int j = 0; j < 4; ++j) {
            int idx = (int)floorf((e[j] - mnv) / wv * 100.0f);
            idx = idx < 0 ? 0 : (idx > 99 ? 99 : idx);
            atomicAdd(&mybins[idx], 1u);
        }
        *(short4*)&xrow[4 * i] = make_short4(f2bf(v.x), f2bf(v.y), f2bf(v.z), f2bf(v.w));
    }
    __syncthreads();

    // bins -> float directly into h_in hist columns (block owns the whole row)
    int b = row / 3, c = row - b * 3;
    if (tid < NBINS) {
        unsigned s = 0;
#pragma unroll
        for (int w2 = 0; w2 < 16; ++w2) s += bins[w2][tid];
        ws[WS_HIN + b * HIN_W + NEMB + c * NBINS + tid] = (float)s;
    }
}

// ================= K2: GEMM = A(bf16) @ base_W.T (split-K, LDS-staged bf16 MFMA) =================
// grid (112, 8), block 256 = 4 waves, all 896 blocks co-resident (3.5/CU at 4/CU residency).
// Epilogue: device-scope atomicAdd straight into h_in (bias pre-set by k_fuse) — no partials.
__global__ __launch_bounds__(256, 4) void k_gemm(const float* __restrict__ ws_all, const float* __restrict__ W,
                                                 float* __restrict__ hin) {
    __shared__ short sA[2][64 * LDA];
    __shared__ short sB[2][64 * LDA];

    int kc = blockIdx.x;
    int n0 = blockIdx.y * NTILE;
    int tid = threadIdx.x;
    int wave = tid >> 6, lane = tid & 63;
    int l15 = lane & 15, quad = lane >> 4;

    const short* Abf = (const short*)(ws_all + WS_XBF);

    // A loader: slab = 64 rows x 8 slots of 8 shorts (16B); 512 slots, 2 passes of 256.
    int arow[2], acol[2];
#pragma unroll
    for (int pp = 0; pp < 2; ++pp) { int slot = pp * 256 + tid; arow[pp] = slot >> 3; acol[pp] = slot & 7; }
    // B loader: slab = 64 rows x 16 float4; 1024 slots, 4 passes of 256.
    int brow[4], bf4[4];
#pragma unroll
    for (int pp = 0; pp < 4; ++pp) { int slot = pp * 256 + tid; brow[pp] = slot >> 4; bf4[pp] = slot & 15; }

    const short* Ab = Abf + (size_t)kc * KC;                           // + row*KDIM + s*BK + col*8
    const float* Bb = W + (size_t)n0 * KDIM + (size_t)kc * KC;         // + row*KDIM + s*BK + f4*4

    f32x4 acc[4];
#pragma unroll
    for (int mt = 0; mt < 4; ++mt) acc[mt] = (f32x4){0.f, 0.f, 0.f, 0.f};

    bf16x8 pfA[2];
    float4 pfB[4];
    // prologue: slab 0
#pragma unroll
    for (int pp = 0; pp < 2; ++pp)
        pfA[pp] = *(const bf16x8*)(Ab + (size_t)arow[pp] * KDIM + acol[pp] * 8);
#pragma unroll
    for (int pp = 0; pp < 4; ++pp)
        pfB[pp] = *(const float4*)(Bb + (size_t)brow[pp] * KDIM + bf4[pp] * 4);
#pragma unroll
    for (int pp = 0; pp < 2; ++pp)
        *(bf16x8*)&sA[0][arow[pp] * LDA + acol[pp] * 8] = pfA[pp];
#pragma unroll
    for (int pp = 0; pp < 4; ++pp)
        *(short4*)&sB[0][brow[pp] * LDA + bf4[pp] * 4] =
            make_short4(f2bf(pfB[pp].x), f2bf(pfB[pp].y), f2bf(pfB[pp].z), f2bf(pfB[pp].w));
    __syncthreads();

    for (int s = 0; s < NSLAB; ++s) {
        int buf = s & 1;
        if (s + 1 < NSLAB) {   // issue next-slab loads: a full slab of compute hides them
            const short* An = Ab + (s + 1) * BK;
            const float* Bn = Bb + (s + 1) * BK;
#pragma unroll
            for (int pp = 0; pp < 2; ++pp)
                pfA[pp] = *(const bf16x8*)(An + (size_t)arow[pp] * KDIM + acol[pp] * 8);
#pragma unroll
            for (int pp = 0; pp < 4; ++pp)
                pfB[pp] = *(const float4*)(Bn + (size_t)brow[pp] * KDIM + bf4[pp] * 4);
        }
#pragma unroll
        for (int ks = 0; ks < 2; ++ks) {
            bf16x8 bf = *(const bf16x8*)&sB[buf][(wave * 16 + l15) * LDA + ks * 32 + quad * 8];
#pragma unroll
            for (int mt = 0; mt < 4; ++mt) {
                bf16x8 af = *(const bf16x8*)&sA[buf][(mt * 16 + l15) * LDA + ks * 32 + quad * 8];
                acc[mt] = __builtin_amdgcn_mfma_f32_16x16x32_bf16(af, bf, acc[mt], 0, 0, 0);
            }
        }
        if (s + 1 < NSLAB) {
            int nbuf = buf ^ 1;
#pragma unroll
            for (int pp = 0; pp < 2; ++pp)
                *(bf16x8*)&sA[nbuf][arow[pp] * LDA + acol[pp] * 8] = pfA[pp];
#pragma unroll
            for (int pp = 0; pp < 4; ++pp)
                *(short4*)&sB[nbuf][brow[pp] * LDA + bf4[pp] * 4] =
                    make_short4(f2bf(pfB[pp].x), f2bf(pfB[pp].y), f2bf(pfB[pp].z), f2bf(pfB[pp].w));
        }
        __syncthreads();
    }

    // C/D layout: col = lane&15 (n), row = quad*4 + reg (m)   [rounds 1-3 validated]
    // 112 chunks atomicAdd per output; fp32 reorder error ~1e-6 rel — inside tolerance.
#pragma unroll
    for (int mt = 0; mt < 4; ++mt) {
        int n = n0 + wave * 16 + l15;
#pragma unroll
        for (int r = 0; r < 4; ++r) {
            int m = mt * 16 + quad * 4 + r;
            atomicAdd(&hin[(size_t)m * HIN_W + n], acc[mt][r]);
        }
    }
}

// ================= K3: h = relu(h_in @ hW.T + hb) — one wave per output =================
__global__ __launch_bounds__(256) void k_layer1(const float* __restrict__ hin, const float* __restrict__ hW,
                                                const float* __restrict__ hb, float* __restrict__ h) {
    int wave = threadIdx.x >> 6, lane = threadIdx.x & 63;
    int gid = blockIdx.x * 4 + wave;           // 25600 outputs
    int b = gid / HID, j = gid - b * HID;
    const float* hr = hin + b * HIN_W;
    const float* wr = hW + j * HIN_W;
    float s = 0.f;
    for (int k = lane; k < HIN_W; k += 64) s += hr[k] * wr[k];
#pragma unroll
    for (int m = 1; m < 64; m <<= 1) s += __shfl_xor(s, m, 64);
    if (lane == 0) h[b * HID + j] = fmaxf(s + hb[j], 0.f);
}

// ================= K4: heads layer-1 (st600 | age400 | gen400 concat) =================
__global__ __launch_bounds__(256) void k_heads1(const float* __restrict__ h,
                                                const float* __restrict__ stW1, const float* __restrict__ stb1,
                                                const float* __restrict__ ageW1, const float* __restrict__ ageb1,
                                                const float* __restrict__ genW1, const float* __restrict__ genb1,
                                                float* __restrict__ t) {
    int wave = threadIdx.x >> 6, lane = threadIdx.x & 63;
    int gid = blockIdx.x * 4 + wave;           // 89600 outputs
    int b = gid / 1400, o = gid - b * 1400;
    const float* wr; float bias;
    if (o < 600)       { wr = stW1  + (size_t)o * 400;          bias = stb1[o]; }
    else if (o < 1000) { wr = ageW1 + (size_t)(o - 600) * 400;  bias = ageb1[o - 600]; }
    else               { wr = genW1 + (size_t)(o - 1000) * 400; bias = genb1[o - 1000]; }
    const float* hr = h + b * HID;
    float s = 0.f;
    for (int k = lane; k < 400; k += 64) s += hr[k] * wr[k];
#pragma unroll
    for (int m = 1; m < 64; m <<= 1) s += __shfl_xor(s, m, 64);
    if (lane == 0) t[b * 1400 + o] = fmaxf(s + bias, 0.f);
}

// ================= K5: heads layer-2 + relu + softmax -> d_out =================
// 64 blocks x 256: 16 outputs x 16 lanes each.
__global__ __launch_bounds__(256) void k_heads2(const float* __restrict__ t,
                                                const float* __restrict__ stW2, const float* __restrict__ stb2,
                                                const float* __restrict__ ageW2, const float* __restrict__ ageb2,
                                                const float* __restrict__ genW2, const float* __restrict__ genb2,
                                                float* __restrict__ out) {
    int b = blockIdx.x;
    int tid = threadIdx.x;
    int o = tid >> 4, sub = tid & 15;          // 16 outputs x 16 lanes
    const float* tr = t + b * 1400;
    const float* wr; const float* tb; float bias; int Klen;
    if (o < 10)      { wr = stW2  + o * 600;        tb = tr;        bias = stb2[o];       Klen = 600; }
    else if (o < 14) { wr = ageW2 + (o - 10) * 400; tb = tr + 600;  bias = ageb2[o - 10]; Klen = 400; }
    else             { wr = genW2 + (o - 14) * 400; tb = tr + 1000; bias = genb2[o - 14]; Klen = 400; }
    float s = 0.f;
    for (int k = sub; k < Klen; k += 16) s += tb[k] * wr[k];
#pragma unroll
    for (int m = 1; m < 16; m <<= 1) s += __shfl_xor(s, m, 64);   // xor within aligned 16-lane group
    __shared__ float lg[16];
    if (sub == 0) lg[o] = fmaxf(s + bias, 0.f);   // relu(logits)
    __syncthreads();
    if (tid == 0) {         // softmax st -> out[b*10]
        float mx = lg[0];
        for (int i = 1; i < 10; ++i) mx = fmaxf(mx, lg[i]);
        float e[10], sum = 0.f;
        for (int i = 0; i < 10; ++i) { e[i] = expf(lg[i] - mx); sum += e[i]; }
        for (int i = 0; i < 10; ++i) out[b * 10 + i] = e[i] / sum;
    } else if (tid == 1) {  // softmax age -> out[640 + b*4]
        float mx = lg[10];
        for (int i = 1; i < 4; ++i) mx = fmaxf(mx, lg[10 + i]);
        float e[4], sum = 0.f;
        for (int i = 0; i < 4; ++i) { e[i] = expf(lg[10 + i] - mx); sum += e[i]; }
        for (int i = 0; i < 4; ++i) out[640 + b * 4 + i] = e[i] / sum;
    } else if (tid == 2) {  // softmax gender -> out[896 + b*2]
        float mx = fmaxf(lg[14], lg[15]);
        float e0 = expf(lg[14] - mx), e1 = expf(lg[15] - mx);
        float sum = e0 + e1;
        out[896 + b * 2 + 0] = e0 / sum;
        out[896 + b * 2 + 1] = e1 / sum;
    }
}

// ================= launch =================
extern "C" void kernel_launch(void* const* d_in, const int* in_sizes, int n_in,
                              void* d_out, int out_size, void* d_ws, size_t ws_size,
                              hipStream_t stream) {
    (void)in_sizes; (void)n_in; (void)out_size; (void)ws_size;
    const float* x      = (const float*)d_in[0];
    const float* base_W = (const float*)d_in[1];
    const float* base_b = (const float*)d_in[2];
    const float* hW     = (const float*)d_in[3];
    const float* hb     = (const float*)d_in[4];
    const float* stW1   = (const float*)d_in[5];
    const float* stb1   = (const float*)d_in[6];
    const float* stW2   = (const float*)d_in[7];
    const float* stb2   = (const float*)d_in[8];
    const float* ageW1  = (const float*)d_in[9];
    const float* ageb1  = (const float*)d_in[10];
    const float* ageW2  = (const float*)d_in[11];
    const float* ageb2  = (const float*)d_in[12];
    const float* genW1  = (const float*)d_in[13];
    const float* genb1  = (const float*)d_in[14];
    const float* genW2  = (const float*)d_in[15];
    const float* genb2  = (const float*)d_in[16];
    float* ws  = (float*)d_ws;
    float* out = (float*)d_out;

    k_fuse  <<<ROWS, 1024, 0, stream>>>(x, base_b, ws);
    k_gemm  <<<dim3(NCHUNK, NEMB / NTILE), 256, 0, stream>>>(ws, base_W, ws + WS_HIN);
    k_layer1<<<(BATCH * HID) / 4, 256, 0, stream>>>(ws + WS_HIN, hW, hb, ws + WS_H);
    k_heads1<<<(BATCH * 1400) / 4, 256, 0, stream>>>(ws + WS_H, stW1, stb1, ageW1, ageb1, genW1, genb1, ws + WS_T);
    k_heads2<<<BATCH, 256, 0, stream>>>(ws + WS_T, stW2, stb2, ageW2, ageb2, genW2, genb2, out);
}